// Round 5
// baseline (160.004 us; speedup 1.0000x reference)
//
#include <hip/hip_runtime.h>

// NonLocalBlockND, algebraically collapsed (linear attention, no softmax):
//   A[b]    = g_p[b] . phi_p[b]^T / M                  [128,128]
//   W_big[b]= W_w . A[b] . W_theta                     [256,256]
//   b_eff[b]= W_w . (A[b] . b_theta) + b_w             [256]
//   out     = BN(W_big[b] . x + b_eff[b]) + x
// phi_p/g_p are pooled conv outputs (pooling is the only nonlinearity).
//
// Round-5: prepw+prepx+convfg fused into convfg2 (reads x/w directly,
// produces xT + phiT + gT in one pass). 5 launches total.
//
// ws layout (bytes):
//   xT   [8][4096][256] bf16 @ 0          (16,777,216)
//   phiT [8][128][1024] bf16 @ 16777216   ( 2,097,152)  pooled, [ci][m]
//   gT   [8][128][1024] bf16 @ 18874368   ( 2,097,152)  pooled, [ci][m]
//   A_g2 [8][128][128]  f32  @ 20971520   (   524,288)
//   T1   [8][128][256]  f32  @ 21495808   ( 1,048,576)
//   Wbig [8][256][256]  bf16 @ 22544384   ( 1,048,576)
//   beff [8][256]       f32  @ 23592960   (     8,192)
// total 23,601,152 B

typedef __attribute__((ext_vector_type(8))) short bf16x8;
typedef __attribute__((ext_vector_type(4))) float f32x4;
typedef unsigned short u16;
typedef unsigned int u32;

constexpr int Cc = 256, NnC = 4096;
constexpr float kEps = 1e-5f;

__device__ __forceinline__ u16 f2b(float f) {
  u32 u = __float_as_uint(f);
  return (u16)((u + 0x7fffu + ((u >> 16) & 1u)) >> 16);
}
__device__ __forceinline__ float b2f(u16 h) {
  return __uint_as_float(((u32)h) << 16);
}
__device__ __forceinline__ u32 pack2(float a, float b) {
  return (u32)f2b(a) | ((u32)f2b(b) << 16);
}
__device__ __forceinline__ void gl16(const void* g, void* l) {
  __builtin_amdgcn_global_load_lds(
      (const __attribute__((address_space(1))) void*)g,
      (__attribute__((address_space(3))) void*)l, 16, 0, 0);
}

// ---------------------------------------------------------------------------
// convfg2: fused {W->bf16, x->xT transpose, phi+g convs, 2x2 maxpool}.
// Grid (nt=32, b=8), 512 threads (8 waves). Output tile 256 o x 128 n, K=256.
// Per 64-c chunk: stage W (cvt), stage x f32 -> LDS, transpose-pack to bf16
// B-tile (swizzled) + write xT (linear), MFMA. Epilogue: bias, pool, write
// phiT ([ci][m]) and gT ([ci][m]).
// ---------------------------------------------------------------------------
__global__ __launch_bounds__(512) void convfg2_kernel(
    const float* __restrict__ x, const float* __restrict__ w_phi,
    const float* __restrict__ w_g, const float* __restrict__ b_phi,
    const float* __restrict__ b_g, u16* __restrict__ xT,
    u16* __restrict__ phiT, u16* __restrict__ gT) {
  __shared__ __align__(16) char pool[83968];
  float* xf = (float*)pool;    // [64][136] f32, 34816 B
  char* Asm = pool + 34816;    // [256 o][64 c] bf16 swizzled, 32768 B
  char* Bsm = pool + 67584;    // [128 n][64 c] bf16 swizzled, 16384 B
  const int nt = blockIdx.x, b = blockIdx.y;
  const int n0 = nt * 128;
  const int t = threadIdx.x;
  const int w = t >> 6, lane = t & 63;
  const int r16 = lane & 15, kg = lane >> 4;
  const int oh = (w & 3) * 64, nh = (w >> 2) * 64;

  f32x4 acc[4][4];
#pragma unroll
  for (int i = 0; i < 4; ++i)
#pragma unroll
    for (int j = 0; j < 4; ++j) acc[i][j] = (f32x4)0.f;

  for (int kt = 0; kt < 4; ++kt) {
    const int c0 = kt * 64;
    // --- stage A: weight chunk [256 o][64 c] f32 -> bf16 swizzled ---
    {
      const int o = t >> 1, cc0 = (t & 1) * 32;
      const float* wsrc = (o < 128) ? (w_phi + (size_t)o * 256 + c0 + cc0)
                                    : (w_g + (size_t)(o - 128) * 256 + c0 + cc0);
#pragma unroll
      for (int j = 0; j < 4; ++j) {
        const float4 v0 = *(const float4*)(wsrc + j * 8);
        const float4 v1 = *(const float4*)(wsrc + j * 8 + 4);
        uint4 p;
        p.x = pack2(v0.x, v0.y);
        p.y = pack2(v0.z, v0.w);
        p.z = pack2(v1.x, v1.y);
        p.w = pack2(v1.z, v1.w);
        *(uint4*)(Asm + ((o * 128 + (cc0 + j * 8) * 2) ^ ((o & 7) << 4))) = p;
      }
    }
    // --- stage x chunk [64 c][128 n] f32 into padded LDS ---
    {
      const int n4 = (t & 31) * 4;
#pragma unroll
      for (int i = 0; i < 4; ++i) {
        const int cc = (t >> 5) + i * 16;
        const float4 v =
            *(const float4*)(x + (size_t)(b * Cc + c0 + cc) * NnC + n0 + n4);
        *(float4*)(xf + cc * 136 + n4) = v;
      }
    }
    __syncthreads();
    // --- transpose+convert -> Bsm (swizzled) and xT (linear global) ---
    {
      const int c8 = (t & 7) * 8;
#pragma unroll
      for (int i = 0; i < 2; ++i) {
        const int n = (t >> 3) + i * 64;
        float f[8];
#pragma unroll
        for (int cc = 0; cc < 8; ++cc) f[cc] = xf[(c8 + cc) * 136 + n];
        uint4 p;
        p.x = pack2(f[0], f[1]);
        p.y = pack2(f[2], f[3]);
        p.z = pack2(f[4], f[5]);
        p.w = pack2(f[6], f[7]);
        *(uint4*)(Bsm + ((n * 128 + c8 * 2) ^ ((n & 7) << 4))) = p;
        *(uint4*)(xT + (size_t)(b * NnC + n0 + n) * Cc + c0 + c8) = p;
      }
    }
    __syncthreads();
    // --- MFMA: 2 k-slices of 32 ---
#pragma unroll
    for (int ks = 0; ks < 2; ++ks) {
      bf16x8 af[4], bfr[4];
#pragma unroll
      for (int f = 0; f < 4; ++f) {
        const int o = oh + f * 16 + r16;
        af[f] = *(const bf16x8*)(Asm + ((o * 128 + ks * 64 + kg * 16) ^
                                        ((o & 7) << 4)));
        const int n = nh + f * 16 + r16;
        bfr[f] = *(const bf16x8*)(Bsm + ((n * 128 + ks * 64 + kg * 16) ^
                                         ((n & 7) << 4)));
      }
#pragma unroll
      for (int fo = 0; fo < 4; ++fo)
#pragma unroll
        for (int fn = 0; fn < 4; ++fn)
          acc[fo][fn] = __builtin_amdgcn_mfma_f32_16x16x32_bf16(
              af[fo], bfr[fn], acc[fo][fn], 0, 0, 0);
    }
    __syncthreads();
  }

  // --- epilogue: bias, bounce [128 n][256 o] bf16 tile, pool, write ---
  u16* tile = (u16*)pool;  // 64 KB, swizzled rows of 512 B
#pragma unroll
  for (int fo = 0; fo < 4; ++fo) {
    const int obase = oh + fo * 16 + kg * 4;
    const float* bias = (obase < 128) ? (b_phi + obase) : (b_g + obase - 128);
    const float b0 = bias[0], b1 = bias[1], b2 = bias[2], b3 = bias[3];
#pragma unroll
    for (int fn = 0; fn < 4; ++fn) {
      const int n = nh + fn * 16 + r16;
      const f32x4 v = acc[fo][fn];
      uint2 p;
      p.x = pack2(v.x + b0, v.y + b1);
      p.y = pack2(v.z + b2, v.w + b3);
      *(uint2*)((char*)tile + ((n * 512 + obase * 2) ^ ((n & 7) << 4))) = p;
    }
  }
  __syncthreads();
  {
    const int tsel = t >> 8;  // 0: phi, 1: g
    const int r = t & 255;
    const int ci = r >> 1, half = r & 1;
    const int o2 = (tsel * 128 + ci) * 2;
    u16* dst = tsel ? gT : phiT;
#pragma unroll
    for (int i = 0; i < 16; ++i) {
      const int mw = half * 16 + i;
      const int n00 = 2 * mw;
      const float v0 = b2f(*(const u16*)((const char*)tile +
                                         ((n00 * 512 + o2) ^ ((n00 & 7) << 4))));
      const float v1 = b2f(*(const u16*)((const char*)tile +
                                         (((n00 + 1) * 512 + o2) ^
                                          (((n00 + 1) & 7) << 4))));
      const float v2 = b2f(*(const u16*)((const char*)tile +
                                         (((n00 + 64) * 512 + o2) ^
                                          (((n00 + 64) & 7) << 4))));
      const float v3 = b2f(*(const u16*)((const char*)tile +
                                         (((n00 + 65) * 512 + o2) ^
                                          (((n00 + 65) & 7) << 4))));
      const float mx = fmaxf(fmaxf(v0, v1), fmaxf(v2, v3));
      dst[(size_t)(b * 128 + ci) * 1024 + nt * 32 + mw] = f2b(mx);
    }
  }
}

// ---------------------------------------------------------------------------
// g2: A_g2[b][ci][c] = (1/M) sum_m gT[b][ci][m] * phiT[b][c][m].  K=1024.
// grid (2 c-halves, 8 b), 4 waves, 64-m chunks double-buffered.
// LDS per buffer: A = 128 rows x 128 B = 16384 B, B = 64 rows x 128 B.
// ---------------------------------------------------------------------------
__global__ __launch_bounds__(256) void g2_kernel(const u16* __restrict__ phiT,
                                                 const u16* __restrict__ gT,
                                                 float* __restrict__ A_g2) {
  __shared__ u16 sm[2][12288];
  const int ch0 = blockIdx.x * 64, b = blockIdx.y;
  const int tid = threadIdx.x;
  const int w = tid >> 6, lane = tid & 63;
  const int r16 = lane & 15, kg = lane >> 4;
  const int cih = (w & 1) * 64, cch = (w >> 1) * 32;

  auto stage = [&](int buf, int m0) {
#pragma unroll
    for (int i = 0; i < 4; ++i) {
      const int lin = i * 4096 + tid * 16;
      const int row = lin >> 7, byte = lin & 127;
      gl16((const char*)gT + ((size_t)(b * 128 + row) * 1024 + m0) * 2 +
               (byte ^ ((row & 7) << 4)),
           (char*)&sm[buf][0] + lin);
    }
#pragma unroll
    for (int i = 0; i < 2; ++i) {
      const int lin = i * 4096 + tid * 16;
      const int row = lin >> 7, byte = lin & 127;
      gl16((const char*)phiT + ((size_t)(b * 128 + ch0 + row) * 1024 + m0) * 2 +
               (byte ^ ((row & 7) << 4)),
           (char*)&sm[buf][8192] + lin);  // B region at byte 16384
    }
  };

  f32x4 acc[4][2];
#pragma unroll
  for (int i = 0; i < 4; ++i)
#pragma unroll
    for (int j = 0; j < 2; ++j) acc[i][j] = (f32x4)0.f;

  stage(0, 0);
  __syncthreads();
  for (int kt = 0; kt < 16; ++kt) {
    if (kt < 15) stage((kt + 1) & 1, (kt + 1) * 64);
    const char* A = (const char*)&sm[kt & 1][0];
    const char* Bp = A + 16384;
#pragma unroll
    for (int ks = 0; ks < 2; ++ks) {
      bf16x8 af[4], bfr[2];
#pragma unroll
      for (int f = 0; f < 4; ++f) {
        const int o = cih + f * 16 + r16;
        af[f] = *(const bf16x8*)(A + ((o * 128 + ks * 64 + kg * 16) ^
                                      ((o & 7) << 4)));
      }
#pragma unroll
      for (int f = 0; f < 2; ++f) {
        const int lc = cch + f * 16 + r16;
        bfr[f] = *(const bf16x8*)(Bp + ((lc * 128 + ks * 64 + kg * 16) ^
                                        ((lc & 7) << 4)));
      }
#pragma unroll
      for (int fo = 0; fo < 4; ++fo)
#pragma unroll
        for (int fn = 0; fn < 2; ++fn)
          acc[fo][fn] = __builtin_amdgcn_mfma_f32_16x16x32_bf16(
              af[fo], bfr[fn], acc[fo][fn], 0, 0, 0);
    }
    __syncthreads();
  }

  constexpr float scl = 1.f / 1024.f;
#pragma unroll
  for (int fo = 0; fo < 4; ++fo) {
#pragma unroll
    for (int r = 0; r < 4; ++r) {
      const int ci = cih + fo * 16 + kg * 4 + r;
#pragma unroll
      for (int fn = 0; fn < 2; ++fn) {
        const int c = ch0 + cch + fn * 16 + r16;
        A_g2[(size_t)b * 16384 + ci * 128 + c] = acc[fo][fn][r] * scl;
      }
    }
  }
}

// ---------------------------------------------------------------------------
// t1: T1[b][ci][j] = sum_c A_g2[b][ci][c] * w_theta[c][j].  fp32, tiny.
// ---------------------------------------------------------------------------
__global__ __launch_bounds__(256) void t1_kernel(const float* __restrict__ A_g2,
                                                 const float* __restrict__ w_theta,
                                                 float* __restrict__ T1) {
  __shared__ float As[16][128];
  __shared__ float Ws[128][17];
  const int tile = blockIdx.x, b = blockIdx.y;
  const int ci0 = (tile >> 4) * 16, j0 = (tile & 15) * 16;
  const int t = threadIdx.x;
#pragma unroll
  for (int i = 0; i < 8; ++i) {
    const int idx = t + i * 256;
    As[idx >> 7][idx & 127] =
        A_g2[(size_t)b * 16384 + (ci0 + (idx >> 7)) * 128 + (idx & 127)];
    Ws[idx >> 4][idx & 15] = w_theta[(idx >> 4) * 256 + j0 + (idx & 15)];
  }
  __syncthreads();
  const int tci = t >> 4, tj = t & 15;
  float s = 0.f;
#pragma unroll 8
  for (int c = 0; c < 128; ++c) s = fmaf(As[tci][c], Ws[c][tj], s);
  T1[(size_t)b * 32768 + (ci0 + tci) * 256 + j0 + tj] = s;
}

// ---------------------------------------------------------------------------
// wbig: Wbig[b][o][j] = bf16( sum_ci w_w[o][ci] * T1[b][ci][j] )
// tile 256: beff[b][o] = w_w[o][:] . (A_g2[b] . b_theta) + b_w[o]
// ---------------------------------------------------------------------------
__global__ __launch_bounds__(256) void wbig_kernel(
    const float* __restrict__ T1, const float* __restrict__ A_g2,
    const float* __restrict__ w_w, const float* __restrict__ b_theta,
    const float* __restrict__ b_w, u16* __restrict__ Wbig,
    float* __restrict__ beff) {
  __shared__ float Ws2[16][128];
  __shared__ float T1s[128][17];
  __shared__ float v1[128];
  const int tile = blockIdx.x, b = blockIdx.y;
  const int t = threadIdx.x;
  if (tile < 256) {
    const int o0 = (tile >> 4) * 16, j0 = (tile & 15) * 16;
#pragma unroll
    for (int i = 0; i < 8; ++i) {
      const int idx = t + i * 256;
      Ws2[idx >> 7][idx & 127] = w_w[(o0 + (idx >> 7)) * 128 + (idx & 127)];
      T1s[idx >> 4][idx & 15] =
          T1[(size_t)b * 32768 + (idx >> 4) * 256 + j0 + (idx & 15)];
    }
    __syncthreads();
    const int to = t >> 4, tj = t & 15;
    float s = 0.f;
#pragma unroll 8
    for (int c = 0; c < 128; ++c) s = fmaf(Ws2[to][c], T1s[c][tj], s);
    Wbig[(size_t)b * 65536 + (o0 + to) * 256 + j0 + tj] = f2b(s);
  } else {
    if (t < 128) {
      float s = 0.f;
      for (int c = 0; c < 128; ++c)
        s = fmaf(A_g2[(size_t)b * 16384 + t * 128 + c], b_theta[c], s);
      v1[t] = s;
    }
    __syncthreads();
    float s2 = b_w[t];
    for (int ci = 0; ci < 128; ++ci) s2 = fmaf(w_w[t * 128 + ci], v1[ci], s2);
    beff[b * 256 + t] = s2;
  }
}

// ---------------------------------------------------------------------------
// final: out[b][o][n] = BN(Wbig[b][o][:] . xT[n][:] + beff) + x.  K=256.
// ---------------------------------------------------------------------------
__global__ __launch_bounds__(256) void final_kernel(
    const u16* __restrict__ xT, const u16* __restrict__ Wbig,
    const float* __restrict__ beff, const float* __restrict__ gamma,
    const float* __restrict__ beta, const float* __restrict__ mean,
    const float* __restrict__ var, const float* __restrict__ x,
    float* __restrict__ out) {
  __shared__ u16 sm[2][2][8192];
  __shared__ float scs[128], offs[128];
  const int mt = blockIdx.x, nt = blockIdx.y, b = blockIdx.z;
  const int n0 = nt * 128;
  const int tid = threadIdx.x;
  const int w = tid >> 6, lane = tid & 63;
  const int r16 = lane & 15, kg = lane >> 4;
  const int oh = (w & 1) * 64, nh = (w >> 1) * 64;

  if (tid < 128) {
    const int o = mt * 128 + tid;
    const float sc = gamma[o] * rsqrtf(var[o] + kEps);
    scs[tid] = sc;
    offs[tid] = beta[o] + (beff[b * 256 + o] - mean[o]) * sc;
  }

  auto stage = [&](int buf, int k0) {
#pragma unroll
    for (int i = 0; i < 4; ++i) {
      const int lin = i * 4096 + tid * 16;
      const int row = lin >> 7, byte = lin & 127;
      gl16((const char*)Wbig + (size_t)b * 131072 +
               (size_t)(mt * 128 + row) * 512 + k0 * 2 +
               (byte ^ ((row & 7) << 4)),
           (char*)&sm[buf][0][0] + lin);
    }
#pragma unroll
    for (int i = 0; i < 4; ++i) {
      const int lin = i * 4096 + tid * 16;
      const int row = lin >> 7, byte = lin & 127;
      gl16((const char*)xT + ((size_t)(b * NnC + n0 + row) * Cc + k0) * 2 +
               (byte ^ ((row & 7) << 4)),
           (char*)&sm[buf][1][0] + lin);
    }
  };

  f32x4 acc[4][4];
#pragma unroll
  for (int i = 0; i < 4; ++i)
#pragma unroll
    for (int j = 0; j < 4; ++j) acc[i][j] = (f32x4)0.f;

  stage(0, 0);
  __syncthreads();
  for (int kt = 0; kt < 4; ++kt) {
    if (kt < 3) stage((kt + 1) & 1, (kt + 1) * 64);
    const char* A = (const char*)&sm[kt & 1][0][0];
    const char* Bm = (const char*)&sm[kt & 1][1][0];
#pragma unroll
    for (int ks = 0; ks < 2; ++ks) {
      bf16x8 af[4], bfr[4];
#pragma unroll
      for (int f = 0; f < 4; ++f) {
        const int o = oh + f * 16 + r16;
        af[f] = *(const bf16x8*)(A + ((o * 128 + ks * 64 + kg * 16) ^
                                      ((o & 7) << 4)));
        const int n = nh + f * 16 + r16;
        bfr[f] = *(const bf16x8*)(Bm + ((n * 128 + ks * 64 + kg * 16) ^
                                        ((n & 7) << 4)));
      }
#pragma unroll
      for (int fo = 0; fo < 4; ++fo)
#pragma unroll
        for (int fn = 0; fn < 4; ++fn)
          acc[fo][fn] = __builtin_amdgcn_mfma_f32_16x16x32_bf16(
              af[fo], bfr[fn], acc[fo][fn], 0, 0, 0);
    }
    __syncthreads();
  }

  const size_t xb = ((size_t)b * Cc + mt * 128) * NnC;
#pragma unroll
  for (int fo = 0; fo < 4; ++fo) {
#pragma unroll
    for (int r = 0; r < 4; ++r) {
      const int ol = oh + fo * 16 + kg * 4 + r;
      const float sc = scs[ol], of = offs[ol];
      const size_t rowoff = xb + (size_t)ol * NnC + n0;
#pragma unroll
      for (int fn = 0; fn < 4; ++fn) {
        const int n = nh + fn * 16 + r16;
        out[rowoff + n] = fmaf(acc[fo][fn][r], sc, of) + x[rowoff + n];
      }
    }
  }
}

// ---------------------------------------------------------------------------
extern "C" void kernel_launch(void* const* d_in, const int* in_sizes, int n_in,
                              void* d_out, int out_size, void* d_ws,
                              size_t ws_size, hipStream_t stream) {
  const float* x = (const float*)d_in[0];
  const float* w_theta = (const float*)d_in[1];
  const float* b_theta = (const float*)d_in[2];
  const float* w_phi = (const float*)d_in[3];
  const float* b_phi = (const float*)d_in[4];
  const float* w_g = (const float*)d_in[5];
  const float* b_g = (const float*)d_in[6];
  const float* w_w = (const float*)d_in[7];
  const float* b_w = (const float*)d_in[8];
  const float* bn_gamma = (const float*)d_in[9];
  const float* bn_beta = (const float*)d_in[10];
  const float* bn_mean = (const float*)d_in[11];
  const float* bn_var = (const float*)d_in[12];
  float* out = (float*)d_out;

  char* ws = (char*)d_ws;
  u16* xT = (u16*)ws;
  u16* phiT = (u16*)(ws + 16777216);
  u16* gT = (u16*)(ws + 18874368);
  float* A_g2 = (float*)(ws + 20971520);
  float* T1 = (float*)(ws + 21495808);
  u16* Wbig = (u16*)(ws + 22544384);
  float* beff = (float*)(ws + 23592960);
  if (ws_size < 23601152ull) return;

  convfg2_kernel<<<dim3(32, 8), dim3(512), 0, stream>>>(
      x, w_phi, w_g, b_phi, b_g, xT, phiT, gT);
  g2_kernel<<<dim3(2, 8), dim3(256), 0, stream>>>(phiT, gT, A_g2);
  t1_kernel<<<dim3(128, 8), dim3(256), 0, stream>>>(A_g2, w_theta, T1);
  wbig_kernel<<<dim3(257, 8), dim3(256), 0, stream>>>(T1, A_g2, w_w, b_theta,
                                                      b_w, Wbig, beff);
  final_kernel<<<dim3(2, 32, 8), dim3(256), 0, stream>>>(
      xT, Wbig, beff, bn_gamma, bn_beta, bn_mean, bn_var, x, out);
}